// Round 8
// baseline (167.499 us; speedup 1.0000x reference)
//
#include <hip/hip_runtime.h>
#include <cmath>

// GAT layer: N=4096 nodes, FIN=128, F=64 per head, H=8 heads.
//   k0: pack A -> masks in TWO layouts: bits[row][word] and bitsT[word][row]
//       (transposed makes attn's per-ct row-slab read contiguous);
//       + W/X swizzle into MFMA fragment order.
//   k1: feats = X @ W[h] f16 MFMA, fully coalesced fragment streams;
//       factored exps es/esn/et/etn (f16); feats -> MFMA-B-swizzled f16.
//   k2: P = mask * max(es*et, esn*etn) packed f16; denominator via MFMA
//       against all-ones B; PV via mfma 16x16x32. Software-pipelined:
//       explicit next-ct register prefetch (launch_bounds(256,3) gives the
//       VGPR headroom; R7's 64-VGPR squeeze serialized load->use per iter).

#define NN 4096
#define FIN 128
#define FF 64
#define HH 8

typedef _Float16 h2 __attribute__((ext_vector_type(2)));
typedef _Float16 h4 __attribute__((ext_vector_type(4)));
typedef _Float16 h8 __attribute__((ext_vector_type(8)));
typedef float f32x2 __attribute__((ext_vector_type(2)));
typedef float f32x4 __attribute__((ext_vector_type(4)));

union H8 {
  h8 v;
  h2 p[4];
};
union H4 {
  h4 v;
  h2 p[2];
};

// ---------------------------------------------------------------- kernel 0
__global__ __launch_bounds__(256) void pack_kernel(
    const int* __restrict__ A, const float* __restrict__ W,
    const float* __restrict__ X, unsigned long long* __restrict__ bits,
    unsigned long long* __restrict__ bitsT, _Float16* __restrict__ Wsw,
    _Float16* __restrict__ Xsw) {
  const int b = blockIdx.x;
  const int tid = threadIdx.x;
  const int wave = tid >> 6, lane = tid & 63;
  if (b < NN) {
    __shared__ int ldsT[4][4][256];
    const int* ar = A + (size_t)b * NN;
    int4 v[4];
#pragma unroll
    for (int it = 0; it < 4; ++it) {
      const int g = wave * 4 + it;
      v[it] = *(const int4*)(ar + g * 256 + lane * 4);
    }
#pragma unroll
    for (int it = 0; it < 4; ++it) *(int4*)&ldsT[wave][it][lane * 4] = v[it];
    unsigned long long* br = bits + ((size_t)b << 6);
#pragma unroll
    for (int it = 0; it < 4; ++it) {
      const int g = wave * 4 + it;
      int w0 = ldsT[wave][it][0 * 64 + lane];
      int w1 = ldsT[wave][it][1 * 64 + lane];
      int w2 = ldsT[wave][it][2 * 64 + lane];
      int w3 = ldsT[wave][it][3 * 64 + lane];
      unsigned long long m0 = __ballot(w0 != 0);
      unsigned long long m1 = __ballot(w1 != 0);
      unsigned long long m2 = __ballot(w2 != 0);
      unsigned long long m3 = __ballot(w3 != 0);
      if (lane == 0) {
        ulonglong2 p0 = {m0, m1}, p1 = {m2, m3};
        *(ulonglong2*)(br + g * 4 + 0) = p0;
        *(ulonglong2*)(br + g * 4 + 2) = p1;
        bitsT[(size_t)(g * 4 + 0) * NN + b] = m0;
        bitsT[(size_t)(g * 4 + 1) * NN + b] = m1;
        bitsT[(size_t)(g * 4 + 2) * NN + b] = m2;
        bitsT[(size_t)(g * 4 + 3) * NN + b] = m3;
      }
    }
  } else if (b < NN + 2) {
    const int h0 = (b - NN) * 4;
    for (int h = h0; h < h0 + 4; ++h) {
      for (int c = tid; c < 1024; c += 256) {  // (kt, nb, lane)
        int ln = c & 63, nb = (c >> 6) & 3, kt = c >> 8;
        int f = nb * 16 + (ln & 15);
        int k0 = kt * 32 + (ln >> 4) * 8;
        h8 v;
#pragma unroll
        for (int j = 0; j < 8; ++j)
          v[j] = (_Float16)W[((size_t)(h * FIN) + k0 + j) * FF + f];
        *(h8*)(Wsw + ((size_t)(((h * 4 + kt) * 4 + nb) * 64 + ln)) * 8) = v;
      }
    }
  } else {
    const int tile = (b - NN - 2) * 4 + wave;  // 16-row tile, 0..255
    const int l16 = lane & 15, quad = lane >> 4;
    const float* xr = X + (size_t)(tile * 16 + l16) * FIN;
#pragma unroll
    for (int kt = 0; kt < 4; ++kt) {
      int k0 = kt * 32 + quad * 8;
      f32x4 x0 = *(const f32x4*)(xr + k0);
      f32x4 x1 = *(const f32x4*)(xr + k0 + 4);
      h8 v = {(_Float16)x0[0], (_Float16)x0[1], (_Float16)x0[2],
              (_Float16)x0[3], (_Float16)x1[0], (_Float16)x1[1],
              (_Float16)x1[2], (_Float16)x1[3]};
      *(h8*)(Xsw + ((size_t)((tile * 4 + kt) * 64 + lane)) * 8) = v;
    }
  }
}

// ---------------------------------------------------------------- kernel 1
__global__ __launch_bounds__(256) void feats_kernel(
    const _Float16* __restrict__ Xsw, const _Float16* __restrict__ Wsw,
    const float* __restrict__ a_self, const float* __restrict__ a_neigh,
    _Float16* __restrict__ feats_sw, _Float16* __restrict__ es_h,
    _Float16* __restrict__ esn_h, _Float16* __restrict__ et_h,
    _Float16* __restrict__ etn_h) {
  const int h = blockIdx.y;
  const int tid = threadIdx.x, wave = tid >> 6, lane = tid & 63;
  const int l16 = lane & 15, quad = lane >> 4;
  const int rt = blockIdx.x * 4 + wave;  // 16-row tile
  const int r0 = rt * 16;

  f32x4 acc[4];
#pragma unroll
  for (int nb = 0; nb < 4; ++nb) acc[nb] = (f32x4){0.f, 0.f, 0.f, 0.f};

  const _Float16* xp = Xsw + ((size_t)(rt * 4) * 64 + lane) * 8;
  const _Float16* wp = Wsw + ((size_t)(h * 16) * 64 + lane) * 8;
  h8 Af[4];
#pragma unroll
  for (int kt = 0; kt < 4; ++kt) Af[kt] = *(const h8*)(xp + kt * 512);
#pragma unroll
  for (int kt = 0; kt < 4; ++kt)
#pragma unroll
    for (int nb = 0; nb < 4; ++nb) {
      h8 Bf = *(const h8*)(wp + (kt * 4 + nb) * 512);
      acc[nb] = __builtin_amdgcn_mfma_f32_16x16x32_f16(Af[kt], Bf, acc[nb], 0, 0, 0);
    }

  float as[4], an[4];
#pragma unroll
  for (int nb = 0; nb < 4; ++nb) {
    as[nb] = a_self[h * FF + nb * 16 + l16];
    an[nb] = a_neigh[h * FF + nb * 16 + l16];
  }
#pragma unroll
  for (int r = 0; r < 4; ++r) {
    float ps = acc[0][r] * as[0] + acc[1][r] * as[1] + acc[2][r] * as[2] +
               acc[3][r] * as[3];
    float pn = acc[0][r] * an[0] + acc[1][r] * an[1] + acc[2][r] * an[2] +
               acc[3][r] * an[3];
#pragma unroll
    for (int m = 1; m <= 8; m <<= 1) {
      ps += __shfl_xor(ps, m, 64);
      pn += __shfl_xor(pn, m, 64);
    }
    if (l16 == 0) {
      int node = h * NN + r0 + quad * 4 + r;
      es_h[node] = (_Float16)__expf(ps - 2.0f);
      esn_h[node] = (_Float16)__expf(0.2f * ps - 2.0f);
      et_h[node] = (_Float16)__expf(pn - 2.0f);
      etn_h[node] = (_Float16)__expf(0.2f * pn - 2.0f);
    }
  }

  const int kb = r0 >> 5;
  const int quadA = ((r0 >> 4) & 1) * 2 + (quad >> 1);
  const int jbase = (quad & 1) << 2;
#pragma unroll
  for (int nb = 0; nb < 4; ++nb) {
    h4 v = {(_Float16)acc[nb][0], (_Float16)acc[nb][1], (_Float16)acc[nb][2],
            (_Float16)acc[nb][3]};
    size_t off = ((size_t)((h * 128 + kb) * 4 + nb) << 9) +
                 ((quadA * 16 + l16) << 3) + jbase;
    *(h4*)(feats_sw + off) = v;
  }
}

// ---------------------------------------------------------------- kernel 2
// grid 1024 = rb*8 + h; 32 rows/block; 4 waves x 16 cts.
// Explicit register prefetch of the next ct stage (ILP over TLP).
struct CtD {
  uint2 b0, b1;                 // bits for rg0/rg1 rows (transposed layout)
  h8 ET0, ETN0, ET1, ETN1;      // neighbor exps per kf
  h8 B0[4], B1[4];              // feats B-frags per kf
};

static __device__ __forceinline__ CtD load_ct(
    const unsigned long long* __restrict__ btp,
    const _Float16* __restrict__ etp, const _Float16* __restrict__ etnp,
    const _Float16* __restrict__ fb, int ct, int rowbase) {
  CtD s;
  const unsigned long long* bp = btp + (size_t)ct * NN + rowbase;
  s.b0 = *(const uint2*)(bp);
  s.b1 = *(const uint2*)(bp + 16);
  const _Float16* e = etp + (ct << 6);
  const _Float16* en = etnp + (ct << 6);
  s.ET0 = *(const h8*)(e);
  s.ET1 = *(const h8*)(e + 32);
  s.ETN0 = *(const h8*)(en);
  s.ETN1 = *(const h8*)(en + 32);
  const _Float16* fk = fb + ((size_t)ct << 12);
#pragma unroll
  for (int nb = 0; nb < 4; ++nb) {
    s.B0[nb] = *(const h8*)(fk + nb * 512);
    s.B1[nb] = *(const h8*)(fk + 2048 + nb * 512);
  }
  return s;
}

__global__ __launch_bounds__(256, 3) void attn_kernel(
    const unsigned long long* __restrict__ bitsT,
    const _Float16* __restrict__ feats_sw, const _Float16* __restrict__ es_h,
    const _Float16* __restrict__ esn_h, const _Float16* __restrict__ et_h,
    const _Float16* __restrict__ etn_h, const float* __restrict__ bias,
    float* __restrict__ out) {
  const int bid = blockIdx.x;
  const int h = bid & 7, n0 = (bid >> 3) << 5;  // 32-row tile
  const int tid = threadIdx.x, wave = tid >> 6, lane = tid & 63;
  const int l16 = lane & 15, quad = lane >> 4;

  __shared__ h4 lut16[16];           // 16 x 8B = exactly 32 banks
  __shared__ float accL[4][16][66];  // 16.9 KB (phase-sized)
  __shared__ float denL[4][32];
  if (tid < 16) {
    h4 m;
#pragma unroll
    for (int j = 0; j < 4; ++j) m[j] = (_Float16)((tid >> j) & 1);
    lut16[tid] = m;
  }
  __syncthreads();

  h2 esp[2], esnp[2];
#pragma unroll
  for (int rg = 0; rg < 2; ++rg) {
    _Float16 e = es_h[h * NN + n0 + rg * 16 + l16];
    _Float16 en = esn_h[h * NN + n0 + rg * 16 + l16];
    esp[rg] = (h2){e, e};
    esnp[rg] = (h2){en, en};
  }

  f32x4 acc[2][4];
  f32x4 accd[2];
#pragma unroll
  for (int rg = 0; rg < 2; ++rg) {
    accd[rg] = (f32x4){0.f, 0.f, 0.f, 0.f};
#pragma unroll
    for (int nb = 0; nb < 4; ++nb) acc[rg][nb] = (f32x4){0.f, 0.f, 0.f, 0.f};
  }
  const h8 onesB = {(_Float16)1.f, (_Float16)1.f, (_Float16)1.f,
                    (_Float16)1.f, (_Float16)1.f, (_Float16)1.f,
                    (_Float16)1.f, (_Float16)1.f};

  const int rowbase = n0 + l16;
  const _Float16* etp = et_h + h * NN + (quad << 3);
  const _Float16* etnp = etn_h + h * NN + (quad << 3);
  const _Float16* fb = feats_sw + ((size_t)h << 18) + (lane << 3);

  CtD cur = load_ct(bitsT, etp, etnp, fb, wave, rowbase);

#pragma unroll 1
  for (int i = 0; i < 16; ++i) {
    CtD nxt;
    if (i < 15) nxt = load_ct(bitsT, etp, etnp, fb, wave + (i + 1) * 4, rowbase);
#pragma unroll
    for (int kf = 0; kf < 2; ++kf) {
      const H8 ET = {kf ? cur.ET1 : cur.ET0};
      const H8 ETN = {kf ? cur.ETN1 : cur.ETN0};
      const h8* B = kf ? cur.B1 : cur.B0;
#pragma unroll
      for (int rg = 0; rg < 2; ++rg) {
        const uint2 bb = rg ? cur.b1 : cur.b0;
        unsigned word = kf ? bb.y : bb.x;
        unsigned byt = (word >> (quad << 3)) & 0xFFu;
        H4 mlo, mhi;
        mlo.v = lut16[byt & 15u];
        mhi.v = lut16[byt >> 4];
        H8 P;
#pragma unroll
        for (int p = 0; p < 4; ++p) {
          h2 a = esp[rg] * ET.p[p];
          h2 b = esnp[rg] * ETN.p[p];
          h2 r = __builtin_elementwise_max(a, b);
          P.p[p] = r * (p < 2 ? mlo.p[p] : mhi.p[p - 2]);
        }
        acc[rg][0] =
            __builtin_amdgcn_mfma_f32_16x16x32_f16(P.v, B[0], acc[rg][0], 0, 0, 0);
        acc[rg][1] =
            __builtin_amdgcn_mfma_f32_16x16x32_f16(P.v, B[1], acc[rg][1], 0, 0, 0);
        acc[rg][2] =
            __builtin_amdgcn_mfma_f32_16x16x32_f16(P.v, B[2], acc[rg][2], 0, 0, 0);
        acc[rg][3] =
            __builtin_amdgcn_mfma_f32_16x16x32_f16(P.v, B[3], acc[rg][3], 0, 0, 0);
        accd[rg] =
            __builtin_amdgcn_mfma_f32_16x16x32_f16(P.v, onesB, accd[rg], 0, 0, 0);
      }
    }
    cur = nxt;
  }

  if (l16 == 0) {
#pragma unroll
    for (int rg = 0; rg < 2; ++rg)
#pragma unroll
      for (int r = 0; r < 4; ++r)
        denL[wave][rg * 16 + quad * 4 + r] = accd[rg][r];
  }

  const int erow = tid >> 4, ec0 = (tid & 15) << 2;
#pragma unroll
  for (int ph = 0; ph < 2; ++ph) {
    __syncthreads();
#pragma unroll
    for (int nb = 0; nb < 4; ++nb)
#pragma unroll
      for (int r = 0; r < 4; ++r)
        accL[wave][quad * 4 + r][nb * 16 + l16] = acc[ph][nb][r];
    __syncthreads();
    const int grow = ph * 16 + erow;
    float dn = denL[0][grow] + denL[1][grow] + denL[2][grow] + denL[3][grow];
    float inv = 1.0f / dn;  // self loop -> dn > 0
    f32x2 v0 = (f32x2){0.f, 0.f}, v1 = (f32x2){0.f, 0.f};
#pragma unroll
    for (int w = 0; w < 4; ++w) {
      v0 += *(const f32x2*)&accL[w][erow][ec0];
      v1 += *(const f32x2*)&accL[w][erow][ec0 + 2];
    }
    const f32x4 bv = *(const f32x4*)(bias + h * FF + ec0);
    f32x4 v = {v0[0], v0[1], v1[0], v1[1]};
#pragma unroll
    for (int i = 0; i < 4; ++i) {
      float x = v[i] * inv + bv[i];
      v[i] = x > 0.f ? x : (__expf(x) - 1.0f);
    }
    *(f32x4*)(out + (size_t)(n0 + grow) * (HH * FF) + h * FF + ec0) = v;
  }
}

// ---------------------------------------------------------------- launch
extern "C" void kernel_launch(void* const* d_in, const int* in_sizes, int n_in,
                              void* d_out, int out_size, void* d_ws,
                              size_t ws_size, hipStream_t stream) {
  const float* X = (const float*)d_in[0];
  const int* A = (const int*)d_in[1];
  const float* W = (const float*)d_in[2];
  const float* b = (const float*)d_in[3];
  const float* a_self = (const float*)d_in[4];
  const float* a_neigh = (const float*)d_in[5];
  float* out = (float*)d_out;

  char* ws = (char*)d_ws;
  unsigned long long* Abits = (unsigned long long*)ws;        // 2 MB
  unsigned long long* bitsT = (unsigned long long*)(ws + (2u << 20));  // 2 MB
  _Float16* feats_sw = (_Float16*)(ws + (4u << 20));          // 4 MB
  _Float16* es_h = (_Float16*)(ws + (8u << 20));              // 64 KB each
  _Float16* esn_h = (_Float16*)(ws + (8u << 20) + (64u << 10));
  _Float16* et_h = (_Float16*)(ws + (8u << 20) + (128u << 10));
  _Float16* etn_h = (_Float16*)(ws + (8u << 20) + (192u << 10));
  _Float16* Wsw = (_Float16*)(ws + (8u << 20) + (256u << 10));   // 128 KB
  _Float16* Xsw = (_Float16*)(ws + (8u << 20) + (384u << 10));   // 1 MB

  pack_kernel<<<NN + 66, 256, 0, stream>>>(A, W, X, Abits, bitsT, Wsw, Xsw);
  feats_kernel<<<dim3(64, 8), 256, 0, stream>>>(Xsw, Wsw, a_self, a_neigh,
                                                feats_sw, es_h, esn_h, et_h,
                                                etn_h);
  attn_kernel<<<1024, 256, 0, stream>>>(bitsT, feats_sw, es_h, esn_h, et_h,
                                        etn_h, b, out);
}

// Round 9
// 145.484 us; speedup vs baseline: 1.1513x; 1.1513x over previous
//
#include <hip/hip_runtime.h>
#include <cmath>

// GAT layer: N=4096 nodes, FIN=128, F=64 per head, H=8 heads.
//   k0: pack A -> transposed masks bitsT[word][row] (contiguous per-ct row
//       slabs for attn); + W/X swizzle into MFMA fragment order.
//   k1: feats = X @ W[h] f16 MFMA, fully coalesced fragment streams;
//       factored exps es/esn/et/etn (f16); feats -> MFMA-B-swizzled f16.
//   k2: P = mask * max(es*et, esn*etn) packed f16; denominator via MFMA
//       against all-ones B; PV via mfma 16x16x32.
//       KEY (R9): rg=4 row-frags per wave (64 rows) -- B vector-load volume
//       = fullB * (N/16) / rg, the only reuse knob; rg 2->4 halves the
//       per-CU vector-memory traffic that pinned attn at ~50 us.
//       launch_bounds(256,2) leaves VGPR headroom so the compiler can
//       overlap next-iteration loads (R7's 64-reg squeeze serialized them).

#define NN 4096
#define FIN 128
#define FF 64
#define HH 8

typedef _Float16 h2 __attribute__((ext_vector_type(2)));
typedef _Float16 h4 __attribute__((ext_vector_type(4)));
typedef _Float16 h8 __attribute__((ext_vector_type(8)));
typedef float f32x2 __attribute__((ext_vector_type(2)));
typedef float f32x4 __attribute__((ext_vector_type(4)));

union H8 {
  h8 v;
  h2 p[4];
};
union H4 {
  h4 v;
  h2 p[2];
};

// ---------------------------------------------------------------- kernel 0
// blocks [0,NN): pack one A-row -> bitsT[word][row] (transposed layout).
// blocks [NN,NN+2): W -> f16 MFMA-B-frag order (4 heads each).
// blocks [NN+2,NN+66): X -> f16 MFMA-A-frag order (4 row-tiles each).
__global__ __launch_bounds__(256) void pack_kernel(
    const int* __restrict__ A, const float* __restrict__ W,
    const float* __restrict__ X, unsigned long long* __restrict__ bitsT,
    _Float16* __restrict__ Wsw, _Float16* __restrict__ Xsw) {
  const int b = blockIdx.x;
  const int tid = threadIdx.x;
  const int wave = tid >> 6, lane = tid & 63;
  if (b < NN) {
    __shared__ int ldsT[4][4][256];
    const int* ar = A + (size_t)b * NN;
    int4 v[4];
#pragma unroll
    for (int it = 0; it < 4; ++it) {
      const int g = wave * 4 + it;
      v[it] = *(const int4*)(ar + g * 256 + lane * 4);
    }
#pragma unroll
    for (int it = 0; it < 4; ++it) *(int4*)&ldsT[wave][it][lane * 4] = v[it];
#pragma unroll
    for (int it = 0; it < 4; ++it) {
      const int g = wave * 4 + it;
      int w0 = ldsT[wave][it][0 * 64 + lane];
      int w1 = ldsT[wave][it][1 * 64 + lane];
      int w2 = ldsT[wave][it][2 * 64 + lane];
      int w3 = ldsT[wave][it][3 * 64 + lane];
      unsigned long long m0 = __ballot(w0 != 0);
      unsigned long long m1 = __ballot(w1 != 0);
      unsigned long long m2 = __ballot(w2 != 0);
      unsigned long long m3 = __ballot(w3 != 0);
      if (lane == 0) {
        bitsT[(size_t)(g * 4 + 0) * NN + b] = m0;
        bitsT[(size_t)(g * 4 + 1) * NN + b] = m1;
        bitsT[(size_t)(g * 4 + 2) * NN + b] = m2;
        bitsT[(size_t)(g * 4 + 3) * NN + b] = m3;
      }
    }
  } else if (b < NN + 2) {
    const int h0 = (b - NN) * 4;
    for (int h = h0; h < h0 + 4; ++h) {
      for (int c = tid; c < 1024; c += 256) {  // (kt, nb, lane)
        int ln = c & 63, nb = (c >> 6) & 3, kt = c >> 8;
        int f = nb * 16 + (ln & 15);
        int k0 = kt * 32 + (ln >> 4) * 8;
        h8 v;
#pragma unroll
        for (int j = 0; j < 8; ++j)
          v[j] = (_Float16)W[((size_t)(h * FIN) + k0 + j) * FF + f];
        *(h8*)(Wsw + ((size_t)(((h * 4 + kt) * 4 + nb) * 64 + ln)) * 8) = v;
      }
    }
  } else {
    const int tile = (b - NN - 2) * 4 + wave;  // 16-row tile, 0..255
    const int l16 = lane & 15, quad = lane >> 4;
    const float* xr = X + (size_t)(tile * 16 + l16) * FIN;
#pragma unroll
    for (int kt = 0; kt < 4; ++kt) {
      int k0 = kt * 32 + quad * 8;
      f32x4 x0 = *(const f32x4*)(xr + k0);
      f32x4 x1 = *(const f32x4*)(xr + k0 + 4);
      h8 v = {(_Float16)x0[0], (_Float16)x0[1], (_Float16)x0[2],
              (_Float16)x0[3], (_Float16)x1[0], (_Float16)x1[1],
              (_Float16)x1[2], (_Float16)x1[3]};
      *(h8*)(Xsw + ((size_t)((tile * 4 + kt) * 64 + lane)) * 8) = v;
    }
  }
}

// ---------------------------------------------------------------- kernel 1
__global__ __launch_bounds__(256) void feats_kernel(
    const _Float16* __restrict__ Xsw, const _Float16* __restrict__ Wsw,
    const float* __restrict__ a_self, const float* __restrict__ a_neigh,
    _Float16* __restrict__ feats_sw, _Float16* __restrict__ es_h,
    _Float16* __restrict__ esn_h, _Float16* __restrict__ et_h,
    _Float16* __restrict__ etn_h) {
  const int h = blockIdx.y;
  const int tid = threadIdx.x, wave = tid >> 6, lane = tid & 63;
  const int l16 = lane & 15, quad = lane >> 4;
  const int rt = blockIdx.x * 4 + wave;  // 16-row tile
  const int r0 = rt * 16;

  f32x4 acc[4];
#pragma unroll
  for (int nb = 0; nb < 4; ++nb) acc[nb] = (f32x4){0.f, 0.f, 0.f, 0.f};

  const _Float16* xp = Xsw + ((size_t)(rt * 4) * 64 + lane) * 8;
  const _Float16* wp = Wsw + ((size_t)(h * 16) * 64 + lane) * 8;
  h8 Af[4];
#pragma unroll
  for (int kt = 0; kt < 4; ++kt) Af[kt] = *(const h8*)(xp + kt * 512);
#pragma unroll
  for (int kt = 0; kt < 4; ++kt)
#pragma unroll
    for (int nb = 0; nb < 4; ++nb) {
      h8 Bf = *(const h8*)(wp + (kt * 4 + nb) * 512);
      acc[nb] = __builtin_amdgcn_mfma_f32_16x16x32_f16(Af[kt], Bf, acc[nb], 0, 0, 0);
    }

  float as[4], an[4];
#pragma unroll
  for (int nb = 0; nb < 4; ++nb) {
    as[nb] = a_self[h * FF + nb * 16 + l16];
    an[nb] = a_neigh[h * FF + nb * 16 + l16];
  }
#pragma unroll
  for (int r = 0; r < 4; ++r) {
    float ps = acc[0][r] * as[0] + acc[1][r] * as[1] + acc[2][r] * as[2] +
               acc[3][r] * as[3];
    float pn = acc[0][r] * an[0] + acc[1][r] * an[1] + acc[2][r] * an[2] +
               acc[3][r] * an[3];
#pragma unroll
    for (int m = 1; m <= 8; m <<= 1) {
      ps += __shfl_xor(ps, m, 64);
      pn += __shfl_xor(pn, m, 64);
    }
    if (l16 == 0) {
      int node = h * NN + r0 + quad * 4 + r;
      es_h[node] = (_Float16)__expf(ps - 2.0f);
      esn_h[node] = (_Float16)__expf(0.2f * ps - 2.0f);
      et_h[node] = (_Float16)__expf(pn - 2.0f);
      etn_h[node] = (_Float16)__expf(0.2f * pn - 2.0f);
    }
  }

  const int kb = r0 >> 5;
  const int quadA = ((r0 >> 4) & 1) * 2 + (quad >> 1);
  const int jbase = (quad & 1) << 2;
#pragma unroll
  for (int nb = 0; nb < 4; ++nb) {
    h4 v = {(_Float16)acc[nb][0], (_Float16)acc[nb][1], (_Float16)acc[nb][2],
            (_Float16)acc[nb][3]};
    size_t off = ((size_t)((h * 128 + kb) * 4 + nb) << 9) +
                 ((quadA * 16 + l16) << 3) + jbase;
    *(h4*)(feats_sw + off) = v;
  }
}

// ---------------------------------------------------------------- kernel 2
// grid 512 = rb*8 + h; 64-row blocks; 4 waves x 16 cts, each wave rg=4
// row-frags (the reuse knob: one B-frag read feeds 4 row-frag MFMAs).
__global__ __launch_bounds__(256, 2) void attn_kernel(
    const unsigned long long* __restrict__ bitsT,
    const _Float16* __restrict__ feats_sw, const _Float16* __restrict__ es_h,
    const _Float16* __restrict__ esn_h, const _Float16* __restrict__ et_h,
    const _Float16* __restrict__ etn_h, const float* __restrict__ bias,
    float* __restrict__ out) {
  const int bid = blockIdx.x;
  const int h = bid & 7, n0 = (bid >> 3) << 6;  // 64-row tile
  const int tid = threadIdx.x, wave = tid >> 6, lane = tid & 63;
  const int l16 = lane & 15, quad = lane >> 4;

  __shared__ h4 lut16[16];           // 16 x 8B = exactly 32 banks
  __shared__ float accL[4][16][66];  // 16.9 KB (phase-sized)
  __shared__ float denL[4][64];
  if (tid < 16) {
    h4 m;
#pragma unroll
    for (int j = 0; j < 4; ++j) m[j] = (_Float16)((tid >> j) & 1);
    lut16[tid] = m;
  }
  __syncthreads();

  h2 esp[4], esnp[4];
#pragma unroll
  for (int rg = 0; rg < 4; ++rg) {
    _Float16 e = es_h[h * NN + n0 + rg * 16 + l16];
    _Float16 en = esn_h[h * NN + n0 + rg * 16 + l16];
    esp[rg] = (h2){e, e};
    esnp[rg] = (h2){en, en};
  }

  f32x4 acc[4][4];
  f32x4 accd[4];
#pragma unroll
  for (int rg = 0; rg < 4; ++rg) {
    accd[rg] = (f32x4){0.f, 0.f, 0.f, 0.f};
#pragma unroll
    for (int nb = 0; nb < 4; ++nb) acc[rg][nb] = (f32x4){0.f, 0.f, 0.f, 0.f};
  }
  const h8 onesB = {(_Float16)1.f, (_Float16)1.f, (_Float16)1.f,
                    (_Float16)1.f, (_Float16)1.f, (_Float16)1.f,
                    (_Float16)1.f, (_Float16)1.f};

  const unsigned long long* btb = bitsT + n0 + l16;
  const _Float16* etp = et_h + h * NN + (quad << 3);
  const _Float16* etnp = etn_h + h * NN + (quad << 3);
  const _Float16* fb = feats_sw + ((size_t)h << 18) + (lane << 3);

#pragma unroll 2
  for (int ct = wave; ct < 64; ct += 4) {
    uint2 bits[4];
#pragma unroll
    for (int rg = 0; rg < 4; ++rg)
      bits[rg] = *(const uint2*)(btb + (size_t)ct * NN + rg * 16);
    const _Float16* fbt = fb + ((size_t)ct << 12);
#pragma unroll
    for (int kf = 0; kf < 2; ++kf) {
      H8 ET, ETN;
      ET.v = *(const h8*)(etp + (ct << 6) + kf * 32);
      ETN.v = *(const h8*)(etnp + (ct << 6) + kf * 32);
      const _Float16* fk = fbt + (kf << 11);
      h8 B0 = *(const h8*)(fk);
      h8 B1 = *(const h8*)(fk + 512);
      h8 B2 = *(const h8*)(fk + 1024);
      h8 B3 = *(const h8*)(fk + 1536);
#pragma unroll
      for (int rg = 0; rg < 4; ++rg) {
        unsigned word = kf ? bits[rg].y : bits[rg].x;
        unsigned byt = (word >> (quad << 3)) & 0xFFu;
        H4 mlo, mhi;
        mlo.v = lut16[byt & 15u];
        mhi.v = lut16[byt >> 4];
        H8 P;
#pragma unroll
        for (int p = 0; p < 4; ++p) {
          h2 a = esp[rg] * ET.p[p];
          h2 b = esnp[rg] * ETN.p[p];
          h2 r = __builtin_elementwise_max(a, b);
          P.p[p] = r * (p < 2 ? mlo.p[p] : mhi.p[p - 2]);
        }
        acc[rg][0] =
            __builtin_amdgcn_mfma_f32_16x16x32_f16(P.v, B0, acc[rg][0], 0, 0, 0);
        acc[rg][1] =
            __builtin_amdgcn_mfma_f32_16x16x32_f16(P.v, B1, acc[rg][1], 0, 0, 0);
        acc[rg][2] =
            __builtin_amdgcn_mfma_f32_16x16x32_f16(P.v, B2, acc[rg][2], 0, 0, 0);
        acc[rg][3] =
            __builtin_amdgcn_mfma_f32_16x16x32_f16(P.v, B3, acc[rg][3], 0, 0, 0);
        accd[rg] =
            __builtin_amdgcn_mfma_f32_16x16x32_f16(P.v, onesB, accd[rg], 0, 0, 0);
      }
    }
  }

  // denominator partials (col-uniform in accd)
  if (l16 == 0) {
#pragma unroll
    for (int rg = 0; rg < 4; ++rg)
#pragma unroll
      for (int r = 0; r < 4; ++r)
        denL[wave][rg * 16 + quad * 4 + r] = accd[rg][r];
  }

  // 4-phase epilogue: 16 rows per phase, 4-way cross-wave reduce
  const int erow = tid >> 4, ec0 = (tid & 15) << 2;
#pragma unroll
  for (int ph = 0; ph < 4; ++ph) {
    __syncthreads();
#pragma unroll
    for (int nb = 0; nb < 4; ++nb)
#pragma unroll
      for (int r = 0; r < 4; ++r)
        accL[wave][quad * 4 + r][nb * 16 + l16] = acc[ph][nb][r];
    __syncthreads();
    const int grow = ph * 16 + erow;
    float dn = denL[0][grow] + denL[1][grow] + denL[2][grow] + denL[3][grow];
    float inv = 1.0f / dn;  // self loop -> dn > 0
    f32x2 v0 = (f32x2){0.f, 0.f}, v1 = (f32x2){0.f, 0.f};
#pragma unroll
    for (int w = 0; w < 4; ++w) {
      v0 += *(const f32x2*)&accL[w][erow][ec0];
      v1 += *(const f32x2*)&accL[w][erow][ec0 + 2];
    }
    const f32x4 bv = *(const f32x4*)(bias + h * FF + ec0);
    f32x4 v = {v0[0], v0[1], v1[0], v1[1]};
#pragma unroll
    for (int i = 0; i < 4; ++i) {
      float x = v[i] * inv + bv[i];
      v[i] = x > 0.f ? x : (__expf(x) - 1.0f);
    }
    *(f32x4*)(out + (size_t)(n0 + grow) * (HH * FF) + h * FF + ec0) = v;
  }
}

// ---------------------------------------------------------------- launch
extern "C" void kernel_launch(void* const* d_in, const int* in_sizes, int n_in,
                              void* d_out, int out_size, void* d_ws,
                              size_t ws_size, hipStream_t stream) {
  const float* X = (const float*)d_in[0];
  const int* A = (const int*)d_in[1];
  const float* W = (const float*)d_in[2];
  const float* b = (const float*)d_in[3];
  const float* a_self = (const float*)d_in[4];
  const float* a_neigh = (const float*)d_in[5];
  float* out = (float*)d_out;

  char* ws = (char*)d_ws;
  unsigned long long* bitsT = (unsigned long long*)ws;        // 2 MB
  _Float16* feats_sw = (_Float16*)(ws + (2u << 20));          // 4 MB
  _Float16* es_h = (_Float16*)(ws + (6u << 20));              // 64 KB each
  _Float16* esn_h = (_Float16*)(ws + (6u << 20) + (64u << 10));
  _Float16* et_h = (_Float16*)(ws + (6u << 20) + (128u << 10));
  _Float16* etn_h = (_Float16*)(ws + (6u << 20) + (192u << 10));
  _Float16* Wsw = (_Float16*)(ws + (6u << 20) + (256u << 10));   // 128 KB
  _Float16* Xsw = (_Float16*)(ws + (6u << 20) + (384u << 10));   // 1 MB

  pack_kernel<<<NN + 66, 256, 0, stream>>>(A, W, X, bitsT, Wsw, Xsw);
  feats_kernel<<<dim3(64, 8), 256, 0, stream>>>(Xsw, Wsw, a_self, a_neigh,
                                                feats_sw, es_h, esn_h, et_h,
                                                etn_h);
  attn_kernel<<<512, 256, 0, stream>>>(bitsT, feats_sw, es_h, esn_h, et_h,
                                       etn_h, b, out);
}